// Round 1
// baseline (4806.541 us; speedup 1.0000x reference)
//
#include <hip/hip_runtime.h>
#include <hip/hip_bf16.h>

// GIN classifier: 3 GIN layers + global add pool + linear classifier.
// Restructured: GEMM before scatter (linearity of segment_sum), so all
// scatters are 128-wide. fp32 baseline (round 0): SGEMM on VALU, atomics
// for scatter/pool, fused BN+ReLU elementwise.

#define N_NODES 100000
#define N_EDGES 800000
#define N_GRAPHS 128

// ---------------- SGEMM: C[M,N] = A[M,K] @ W[K,N] (+bias, relu) ----------------
// BM=64 rows/block, BN=N (128 or 64), BK=32, 256 threads, thread tile TMxTN.
template<int K, int N, bool RELU_BIAS>
__global__ __launch_bounds__(256) void gemm_k(const float* __restrict__ A,
                                              const float* __restrict__ W,
                                              const float* __restrict__ bias,
                                              float* __restrict__ C, int M) {
    constexpr int BM = 64;
    constexpr int BK = 32;
    constexpr int TM = 4;          // 16 * 4 = 64 rows
    constexpr int TN = N / 16;     // 8 (N=128) or 4 (N=64)
    __shared__ float As[BM][BK + 1];             // +1 pad: conflict-free col reads
    __shared__ __align__(16) float Ws[BK][N];

    const int tid = threadIdx.x;
    const int tx = tid & 15;       // col group
    const int ty = tid >> 4;       // row group
    const int row0 = blockIdx.x * BM;

    float acc[TM][TN] = {};

    for (int k0 = 0; k0 < K; k0 += BK) {
        // A tile: 64x32 = 512 float4 -> 2 per thread
        #pragma unroll
        for (int p = 0; p < 2; ++p) {
            int idx = tid + p * 256;
            int r = idx >> 3;          // 0..63
            int c4 = idx & 7;          // 0..7
            float4 v = make_float4(0.f, 0.f, 0.f, 0.f);
            int gr = row0 + r;
            if (gr < M)
                v = *reinterpret_cast<const float4*>(A + (size_t)gr * K + k0 + c4 * 4);
            As[r][c4 * 4 + 0] = v.x; As[r][c4 * 4 + 1] = v.y;
            As[r][c4 * 4 + 2] = v.z; As[r][c4 * 4 + 3] = v.w;
        }
        // W tile: BK x N
        constexpr int WV = BK * N / 4;         // float4 count
        #pragma unroll
        for (int p = 0; p < WV / 256; ++p) {
            int idx = tid + p * 256;
            int r = idx / (N / 4);
            int c4 = idx % (N / 4);
            *reinterpret_cast<float4*>(&Ws[r][c4 * 4]) =
                *reinterpret_cast<const float4*>(W + (size_t)(k0 + r) * N + c4 * 4);
        }
        __syncthreads();
        #pragma unroll
        for (int kk = 0; kk < BK; ++kk) {
            float a[TM], b[TN];
            #pragma unroll
            for (int i = 0; i < TM; ++i) a[i] = As[ty * TM + i][kk];
            #pragma unroll
            for (int j = 0; j < TN; ++j) b[j] = Ws[kk][tx * TN + j];
            #pragma unroll
            for (int i = 0; i < TM; ++i)
                #pragma unroll
                for (int j = 0; j < TN; ++j)
                    acc[i][j] += a[i] * b[j];
        }
        __syncthreads();
    }

    #pragma unroll
    for (int i = 0; i < TM; ++i) {
        int gr = row0 + ty * TM + i;
        if (gr >= M) continue;
        #pragma unroll
        for (int j = 0; j < TN; j += 4) {
            float4 v;
            v.x = acc[i][j + 0]; v.y = acc[i][j + 1];
            v.z = acc[i][j + 2]; v.w = acc[i][j + 3];
            if (RELU_BIAS) {
                int c = tx * TN + j;
                v.x = fmaxf(v.x + bias[c + 0], 0.f);
                v.y = fmaxf(v.y + bias[c + 1], 0.f);
                v.z = fmaxf(v.z + bias[c + 2], 0.f);
                v.w = fmaxf(v.w + bias[c + 3], 0.f);
            }
            *reinterpret_cast<float4*>(C + (size_t)gr * N + tx * TN + j) = v;
        }
    }
}

// ---------------- scatter-add: AGG[dst[e]] += Y[src[e]], D=128 ----------------
__global__ __launch_bounds__(256) void scatter_k(const float* __restrict__ Y,
                                                 const int* __restrict__ src,
                                                 const int* __restrict__ dst,
                                                 float* __restrict__ AGG) {
    unsigned gid = blockIdx.x * 256u + threadIdx.x;  // N_EDGES*32 exactly
    unsigned e = gid >> 5;
    unsigned c4 = (gid & 31) * 4;
    int s = src[e], d = dst[e];
    float4 v = *reinterpret_cast<const float4*>(Y + (size_t)s * 128 + c4);
    float* p = AGG + (size_t)d * 128 + c4;
    atomicAdd(p + 0, v.x); atomicAdd(p + 1, v.y);
    atomicAdd(p + 2, v.z); atomicAdd(p + 3, v.w);
}

// ---------------- fused (1+eps)*Y + AGG + ba -> BN -> ReLU (in-place into Y) --
__global__ __launch_bounds__(256) void fuse_bn_k(float* __restrict__ Y,
                                                 const float* __restrict__ AGG,
                                                 const float* __restrict__ epsp,
                                                 const float* __restrict__ ba,
                                                 const float* __restrict__ g,
                                                 const float* __restrict__ be,
                                                 const float* __restrict__ m,
                                                 const float* __restrict__ v) {
    int gid = blockIdx.x * 256 + threadIdx.x;   // N_NODES*32 exactly
    int c0 = (gid & 31) * 4;
    float ep = 1.0f + epsp[0];
    float4 y = *reinterpret_cast<const float4*>(Y + (size_t)gid * 4);
    float4 a = *reinterpret_cast<const float4*>(AGG + (size_t)gid * 4);
    float o[4];
    float yy[4] = {y.x, y.y, y.z, y.w};
    float aa[4] = {a.x, a.y, a.z, a.w};
    #pragma unroll
    for (int j = 0; j < 4; ++j) {
        int c = c0 + j;
        float sc = g[c] * rsqrtf(v[c] + 1e-5f);
        float t = ep * yy[j] + aa[j] + ba[c] - m[c];
        o[j] = fmaxf(t * sc + be[c], 0.f);
    }
    float4 r = make_float4(o[0], o[1], o[2], o[3]);
    *reinterpret_cast<float4*>(Y + (size_t)gid * 4) = r;
}

// ---------------- global add pool: pooled[batch[n]] += h[n], D=64 -------------
__global__ __launch_bounds__(256) void pool_k(const float* __restrict__ h,
                                              const int* __restrict__ batch,
                                              float* __restrict__ pooled) {
    int gid = blockIdx.x * 256 + threadIdx.x;   // N_NODES*16 exactly
    int n = gid >> 4;
    int c4 = (gid & 15) * 4;
    int b = batch[n];
    float4 v = *reinterpret_cast<const float4*>(h + (size_t)n * 64 + c4);
    float* p = pooled + (size_t)b * 64 + c4;
    atomicAdd(p + 0, v.x); atomicAdd(p + 1, v.y);
    atomicAdd(p + 2, v.z); atomicAdd(p + 3, v.w);
}

// ---------------- classifier: out[G,2] = pooled[G,64] @ wc[64,2] + bc ---------
__global__ __launch_bounds__(256) void classifier_k(const float* __restrict__ pooled,
                                                    const float* __restrict__ wc,
                                                    const float* __restrict__ bc,
                                                    float* __restrict__ out) {
    int t = threadIdx.x;           // 256 = 128 graphs * 2 classes
    int gidx = t >> 1, c = t & 1;
    float s = bc[c];
    #pragma unroll
    for (int k = 0; k < 64; ++k)
        s += pooled[gidx * 64 + k] * wc[k * 2 + c];
    out[gidx * 2 + c] = s;
}

extern "C" void kernel_launch(void* const* d_in, const int* in_sizes, int n_in,
                              void* d_out, int out_size, void* d_ws, size_t ws_size,
                              hipStream_t stream) {
    const float* x     = (const float*)d_in[0];
    const int*   ei    = (const int*)d_in[1];
    const int*   src   = ei;
    const int*   dst   = ei + N_EDGES;
    const int*   batch = (const int*)d_in[2];
    const float* eps1 = (const float*)d_in[3];
    const float* w1a  = (const float*)d_in[4];
    const float* b1a  = (const float*)d_in[5];
    const float* g1   = (const float*)d_in[6];
    const float* be1  = (const float*)d_in[7];
    const float* m1   = (const float*)d_in[8];
    const float* v1   = (const float*)d_in[9];
    const float* w1b  = (const float*)d_in[10];
    const float* b1b  = (const float*)d_in[11];
    const float* eps2 = (const float*)d_in[12];
    const float* w2a  = (const float*)d_in[13];
    const float* b2a  = (const float*)d_in[14];
    const float* g2   = (const float*)d_in[15];
    const float* be2  = (const float*)d_in[16];
    const float* m2   = (const float*)d_in[17];
    const float* v2   = (const float*)d_in[18];
    const float* w2b  = (const float*)d_in[19];
    const float* b2b  = (const float*)d_in[20];
    const float* eps3 = (const float*)d_in[21];
    const float* w3a  = (const float*)d_in[22];
    const float* b3a  = (const float*)d_in[23];
    const float* g3   = (const float*)d_in[24];
    const float* be3  = (const float*)d_in[25];
    const float* m3   = (const float*)d_in[26];
    const float* v3   = (const float*)d_in[27];
    const float* w3b  = (const float*)d_in[28];
    const float* b3b  = (const float*)d_in[29];
    const float* wc   = (const float*)d_in[30];
    const float* bc   = (const float*)d_in[31];
    float* out = (float*)d_out;

    float* ws = (float*)d_ws;
    float* Y      = ws;                        // [100000,128]
    float* AGG    = ws + 12800000;             // [100000,128]
    float* Xn     = ws + 25600000;             // [100000,128]
    float* pooled = ws + 38400000;             // [128,64]

    const int M = N_NODES;
    const int gGemm = (M + 63) / 64;           // 1563
    const int gScat = N_EDGES * 32 / 256;      // 100000
    const int gFuse = M * 32 / 256;            // 12500
    const int gPool = M * 16 / 256;            // 6250
    const size_t aggBytes = (size_t)M * 128 * sizeof(float);

    // ---- layer 1 ----
    gemm_k<384, 128, false><<<gGemm, 256, 0, stream>>>(x, w1a, nullptr, Y, M);
    hipMemsetAsync(AGG, 0, aggBytes, stream);
    scatter_k<<<gScat, 256, 0, stream>>>(Y, src, dst, AGG);
    fuse_bn_k<<<gFuse, 256, 0, stream>>>(Y, AGG, eps1, b1a, g1, be1, m1, v1);
    gemm_k<128, 128, true><<<gGemm, 256, 0, stream>>>(Y, w1b, b1b, Xn, M);

    // ---- layer 2 ----
    gemm_k<128, 128, false><<<gGemm, 256, 0, stream>>>(Xn, w2a, nullptr, Y, M);
    hipMemsetAsync(AGG, 0, aggBytes, stream);
    scatter_k<<<gScat, 256, 0, stream>>>(Y, src, dst, AGG);
    fuse_bn_k<<<gFuse, 256, 0, stream>>>(Y, AGG, eps2, b2a, g2, be2, m2, v2);
    gemm_k<128, 128, true><<<gGemm, 256, 0, stream>>>(Y, w2b, b2b, Xn, M);

    // ---- layer 3 ----
    gemm_k<128, 128, false><<<gGemm, 256, 0, stream>>>(Xn, w3a, nullptr, Y, M);
    hipMemsetAsync(AGG, 0, aggBytes, stream);
    scatter_k<<<gScat, 256, 0, stream>>>(Y, src, dst, AGG);
    fuse_bn_k<<<gFuse, 256, 0, stream>>>(Y, AGG, eps3, b3a, g3, be3, m3, v3);
    gemm_k<128, 64, true><<<gGemm, 256, 0, stream>>>(Y, w3b, b3b, Xn, M);   // [M,64]

    // ---- pool + classifier ----
    hipMemsetAsync(pooled, 0, (size_t)N_GRAPHS * 64 * sizeof(float), stream);
    pool_k<<<gPool, 256, 0, stream>>>(Xn, batch, pooled);
    classifier_k<<<1, 256, 0, stream>>>(pooled, wc, bc, out);
}

// Round 2
// 826.740 us; speedup vs baseline: 5.8138x; 5.8138x over previous
//
#include <hip/hip_runtime.h>
#include <hip/hip_bf16.h>

// GIN classifier: 3 GIN layers + global add pool + linear classifier.
// R1: replace fp32-atomic scatter (84% of runtime) with on-device CSR build
// (int atomics, once per launch) + per-node wave gather fused with BN+ReLU.
// Pool exploits sorted batch -> per-thread running sums, few atomics.

#define N_NODES 100000
#define N_EDGES 800000
#define N_GRAPHS 128
#define NB_SCAN 391   // ceil(N_NODES/256)

// ---------------- SGEMM: C[M,N] = A[M,K] @ W[K,N] (+bias, relu) ----------------
template<int K, int N, bool RELU_BIAS>
__global__ __launch_bounds__(256) void gemm_k(const float* __restrict__ A,
                                              const float* __restrict__ W,
                                              const float* __restrict__ bias,
                                              float* __restrict__ C, int M) {
    constexpr int BM = 64;
    constexpr int BK = 32;
    constexpr int TM = 4;          // 16 * 4 = 64 rows
    constexpr int TN = N / 16;     // 8 (N=128) or 4 (N=64)
    __shared__ float As[BM][BK + 1];
    __shared__ __align__(16) float Ws[BK][N];

    const int tid = threadIdx.x;
    const int tx = tid & 15;
    const int ty = tid >> 4;
    const int row0 = blockIdx.x * BM;

    float acc[TM][TN] = {};

    for (int k0 = 0; k0 < K; k0 += BK) {
        #pragma unroll
        for (int p = 0; p < 2; ++p) {
            int idx = tid + p * 256;
            int r = idx >> 3;
            int c4 = idx & 7;
            float4 v = make_float4(0.f, 0.f, 0.f, 0.f);
            int gr = row0 + r;
            if (gr < M)
                v = *reinterpret_cast<const float4*>(A + (size_t)gr * K + k0 + c4 * 4);
            As[r][c4 * 4 + 0] = v.x; As[r][c4 * 4 + 1] = v.y;
            As[r][c4 * 4 + 2] = v.z; As[r][c4 * 4 + 3] = v.w;
        }
        constexpr int WV = BK * N / 4;
        #pragma unroll
        for (int p = 0; p < WV / 256; ++p) {
            int idx = tid + p * 256;
            int r = idx / (N / 4);
            int c4 = idx % (N / 4);
            *reinterpret_cast<float4*>(&Ws[r][c4 * 4]) =
                *reinterpret_cast<const float4*>(W + (size_t)(k0 + r) * N + c4 * 4);
        }
        __syncthreads();
        #pragma unroll
        for (int kk = 0; kk < BK; ++kk) {
            float a[TM], b[TN];
            #pragma unroll
            for (int i = 0; i < TM; ++i) a[i] = As[ty * TM + i][kk];
            #pragma unroll
            for (int j = 0; j < TN; ++j) b[j] = Ws[kk][tx * TN + j];
            #pragma unroll
            for (int i = 0; i < TM; ++i)
                #pragma unroll
                for (int j = 0; j < TN; ++j)
                    acc[i][j] += a[i] * b[j];
        }
        __syncthreads();
    }

    #pragma unroll
    for (int i = 0; i < TM; ++i) {
        int gr = row0 + ty * TM + i;
        if (gr >= M) continue;
        #pragma unroll
        for (int j = 0; j < TN; j += 4) {
            float4 v;
            v.x = acc[i][j + 0]; v.y = acc[i][j + 1];
            v.z = acc[i][j + 2]; v.w = acc[i][j + 3];
            if (RELU_BIAS) {
                int c = tx * TN + j;
                v.x = fmaxf(v.x + bias[c + 0], 0.f);
                v.y = fmaxf(v.y + bias[c + 1], 0.f);
                v.z = fmaxf(v.z + bias[c + 2], 0.f);
                v.w = fmaxf(v.w + bias[c + 3], 0.f);
            }
            *reinterpret_cast<float4*>(C + (size_t)gr * N + tx * TN + j) = v;
        }
    }
}

// ---------------- CSR build ----------------
__global__ __launch_bounds__(256) void hist_k(const int* __restrict__ dst,
                                              int* __restrict__ deg) {
    int e = blockIdx.x * 256 + threadIdx.x;
    if (e < N_EDGES) atomicAdd(&deg[dst[e]], 1);
}

__global__ __launch_bounds__(256) void scan1_k(const int* __restrict__ deg,
                                               int* __restrict__ tmp,
                                               int* __restrict__ bsum) {
    __shared__ int s[256];
    int i = blockIdx.x * 256 + threadIdx.x;
    int t = threadIdx.x;
    s[t] = (i < N_NODES) ? deg[i] : 0;
    __syncthreads();
    for (int off = 1; off < 256; off <<= 1) {
        int v = (t >= off) ? s[t - off] : 0;
        __syncthreads();
        s[t] += v;
        __syncthreads();
    }
    if (i < N_NODES) tmp[i] = s[t];
    if (t == 255) bsum[blockIdx.x] = s[255];
}

__global__ __launch_bounds__(512) void scan2_k(int* __restrict__ bsum) {
    __shared__ int s[512];
    int t = threadIdx.x;
    s[t] = (t < NB_SCAN) ? bsum[t] : 0;
    __syncthreads();
    for (int off = 1; off < 512; off <<= 1) {
        int v = (t >= off) ? s[t - off] : 0;
        __syncthreads();
        s[t] += v;
        __syncthreads();
    }
    if (t < NB_SCAN) bsum[t] = s[t];
}

// exclusive start = inclusive(tmp) - deg + block_offset
__global__ __launch_bounds__(256) void scan3_k(const int* __restrict__ tmp,
                                               const int* __restrict__ deg,
                                               const int* __restrict__ bsum,
                                               int* __restrict__ row_start) {
    int i = blockIdx.x * 256 + threadIdx.x;
    if (i >= N_NODES) return;
    int boff = (blockIdx.x > 0) ? bsum[blockIdx.x - 1] : 0;
    row_start[i] = tmp[i] - deg[i] + boff;
}

// fill: bumps row_start -> afterwards row_start[n] == row END offset
__global__ __launch_bounds__(256) void fill_k(const int* __restrict__ src,
                                              const int* __restrict__ dst,
                                              int* __restrict__ row_start,
                                              int* __restrict__ csr_src) {
    int e = blockIdx.x * 256 + threadIdx.x;
    if (e >= N_EDGES) return;
    int idx = atomicAdd(&row_start[dst[e]], 1);
    csr_src[idx] = src[e];
}

// ---------- gather neighbors + (1+eps)*own + bias -> BN -> ReLU, D=128 --------
// one wave (64 lanes) per node, 2 cols per lane
__global__ __launch_bounds__(256) void gather_bn_k(const float* __restrict__ Y,
                                                   const int* __restrict__ csr_src,
                                                   const int* __restrict__ row_end,
                                                   const int* __restrict__ deg,
                                                   const float* __restrict__ epsp,
                                                   const float* __restrict__ ba,
                                                   const float* __restrict__ g,
                                                   const float* __restrict__ be,
                                                   const float* __restrict__ m,
                                                   const float* __restrict__ v,
                                                   float* __restrict__ H) {
    int node = blockIdx.x * 4 + (threadIdx.x >> 6);
    int lane = threadIdx.x & 63;
    if (node >= N_NODES) return;
    int end = row_end[node];
    int d = deg[node];
    float accx = 0.f, accy = 0.f;
    for (int j = end - d; j < end; ++j) {
        int s = csr_src[j];
        float2 vv = *reinterpret_cast<const float2*>(Y + (size_t)s * 128 + lane * 2);
        accx += vv.x; accy += vv.y;
    }
    float ep = 1.0f + epsp[0];
    float2 own = *reinterpret_cast<const float2*>(Y + (size_t)node * 128 + lane * 2);
    int c0 = lane * 2;
    float sc0 = g[c0] * rsqrtf(v[c0] + 1e-5f);
    float sc1 = g[c0 + 1] * rsqrtf(v[c0 + 1] + 1e-5f);
    float t0 = ep * own.x + accx + ba[c0] - m[c0];
    float t1 = ep * own.y + accy + ba[c0 + 1] - m[c0 + 1];
    float2 r;
    r.x = fmaxf(t0 * sc0 + be[c0], 0.f);
    r.y = fmaxf(t1 * sc1 + be[c0 + 1], 0.f);
    *reinterpret_cast<float2*>(H + (size_t)node * 128 + c0) = r;
}

// ---------------- pool (batch sorted): running per-thread sums ----------------
__global__ __launch_bounds__(256) void pool_k(const float* __restrict__ h,
                                              const int* __restrict__ batch,
                                              float* __restrict__ pooled) {
    int c = threadIdx.x & 63;
    int r = threadIdx.x >> 6;
    int n0 = blockIdx.x * 256 + r * 64;
    float acc = 0.f;
    int cur = -1;
    for (int i = 0; i < 64; ++i) {
        int n = n0 + i;
        if (n >= N_NODES) break;
        int b = batch[n];
        if (b != cur) {
            if (cur >= 0) atomicAdd(&pooled[cur * 64 + c], acc);
            acc = 0.f;
            cur = b;
        }
        acc += h[(size_t)n * 64 + c];
    }
    if (cur >= 0) atomicAdd(&pooled[cur * 64 + c], acc);
}

// ---------------- classifier ----------------
__global__ __launch_bounds__(256) void classifier_k(const float* __restrict__ pooled,
                                                    const float* __restrict__ wc,
                                                    const float* __restrict__ bc,
                                                    float* __restrict__ out) {
    int t = threadIdx.x;
    int gidx = t >> 1, c = t & 1;
    float s = bc[c];
    #pragma unroll
    for (int k = 0; k < 64; ++k)
        s += pooled[gidx * 64 + k] * wc[k * 2 + c];
    out[gidx * 2 + c] = s;
}

extern "C" void kernel_launch(void* const* d_in, const int* in_sizes, int n_in,
                              void* d_out, int out_size, void* d_ws, size_t ws_size,
                              hipStream_t stream) {
    const float* x     = (const float*)d_in[0];
    const int*   ei    = (const int*)d_in[1];
    const int*   src   = ei;
    const int*   dst   = ei + N_EDGES;
    const int*   batch = (const int*)d_in[2];
    const float* eps1 = (const float*)d_in[3];
    const float* w1a  = (const float*)d_in[4];
    const float* b1a  = (const float*)d_in[5];
    const float* g1   = (const float*)d_in[6];
    const float* be1  = (const float*)d_in[7];
    const float* m1   = (const float*)d_in[8];
    const float* v1   = (const float*)d_in[9];
    const float* w1b  = (const float*)d_in[10];
    const float* b1b  = (const float*)d_in[11];
    const float* eps2 = (const float*)d_in[12];
    const float* w2a  = (const float*)d_in[13];
    const float* b2a  = (const float*)d_in[14];
    const float* g2   = (const float*)d_in[15];
    const float* be2  = (const float*)d_in[16];
    const float* m2   = (const float*)d_in[17];
    const float* v2   = (const float*)d_in[18];
    const float* w2b  = (const float*)d_in[19];
    const float* b2b  = (const float*)d_in[20];
    const float* eps3 = (const float*)d_in[21];
    const float* w3a  = (const float*)d_in[22];
    const float* b3a  = (const float*)d_in[23];
    const float* g3   = (const float*)d_in[24];
    const float* be3  = (const float*)d_in[25];
    const float* m3   = (const float*)d_in[26];
    const float* v3   = (const float*)d_in[27];
    const float* w3b  = (const float*)d_in[28];
    const float* b3b  = (const float*)d_in[29];
    const float* wc   = (const float*)d_in[30];
    const float* bc   = (const float*)d_in[31];
    float* out = (float*)d_out;

    // workspace layout (fits well under R0-proven 153 MB)
    float* ws = (float*)d_ws;
    float* buf0   = ws;                        // [100000,128] f32
    float* buf1   = ws + 12800000;             // [100000,128] f32
    float* pooled = ws + 25600000;             // [128,64]
    int* ideg = (int*)(ws + 25600000 + 8192);  // [100000]
    int* irow = ideg + N_NODES;                // [100000]
    int* itmp = irow + N_NODES;                // [100000] scan scratch
    int* icsr = itmp + N_NODES;                // [800000]
    int* ibsum = icsr + N_EDGES;               // [391]

    const int M = N_NODES;
    const int gGemm = (M + 63) / 64;           // 1563
    const int gEdge = (N_EDGES + 255) / 256;   // 3125
    const int gNode = NB_SCAN;                 // 391
    const int gGath = (M + 3) / 4;             // 25000

    // ---- build CSR (once, reused by all 3 layers) ----
    hipMemsetAsync(ideg, 0, N_NODES * sizeof(int), stream);
    hist_k<<<gEdge, 256, 0, stream>>>(dst, ideg);
    scan1_k<<<gNode, 256, 0, stream>>>(ideg, itmp, ibsum);
    scan2_k<<<1, 512, 0, stream>>>(ibsum);
    scan3_k<<<gNode, 256, 0, stream>>>(itmp, ideg, ibsum, irow);
    fill_k<<<gEdge, 256, 0, stream>>>(src, dst, irow, icsr);
    // now irow[n] == end offset of node n's bucket; start = end - ideg[n]

    // ---- layer 1 ----
    gemm_k<384, 128, false><<<gGemm, 256, 0, stream>>>(x, w1a, nullptr, buf0, M);
    gather_bn_k<<<gGath, 256, 0, stream>>>(buf0, icsr, irow, ideg, eps1, b1a, g1, be1, m1, v1, buf1);
    gemm_k<128, 128, true><<<gGemm, 256, 0, stream>>>(buf1, w1b, b1b, buf1, M);  // in-place safe (block-private rows)

    // ---- layer 2 ----
    gemm_k<128, 128, false><<<gGemm, 256, 0, stream>>>(buf1, w2a, nullptr, buf0, M);
    gather_bn_k<<<gGath, 256, 0, stream>>>(buf0, icsr, irow, ideg, eps2, b2a, g2, be2, m2, v2, buf1);
    gemm_k<128, 128, true><<<gGemm, 256, 0, stream>>>(buf1, w2b, b2b, buf1, M);

    // ---- layer 3 ----
    gemm_k<128, 128, false><<<gGemm, 256, 0, stream>>>(buf1, w3a, nullptr, buf0, M);
    gather_bn_k<<<gGath, 256, 0, stream>>>(buf0, icsr, irow, ideg, eps3, b3a, g3, be3, m3, v3, buf1);
    gemm_k<128, 64, true><<<gGemm, 256, 0, stream>>>(buf1, w3b, b3b, buf0, M);   // [M,64] -> buf0

    // ---- pool + classifier ----
    hipMemsetAsync(pooled, 0, (size_t)N_GRAPHS * 64 * sizeof(float), stream);
    pool_k<<<gNode, 256, 0, stream>>>(buf0, batch, pooled);
    classifier_k<<<1, 256, 0, stream>>>(pooled, wc, bc, out);
}

// Round 3
// 605.357 us; speedup vs baseline: 7.9400x; 1.3657x over previous
//
#include <hip/hip_runtime.h>
#include <hip/hip_bf16.h>

// GIN classifier. R2: bf16 MFMA GEMMs (16x16x32), bf16 activations everywhere,
// weights pre-transposed to Wt[N][K] bf16 so B-frags load straight from L1/L2.
// CSR-gather (R1) kept, now bf16 I/O.

#define N_NODES 100000
#define N_EDGES 800000
#define N_GRAPHS 128
#define NB_SCAN 391   // ceil(N_NODES/256)

typedef __bf16 bf16x8 __attribute__((ext_vector_type(8)));
typedef float f32x4 __attribute__((ext_vector_type(4)));
typedef unsigned short ushort_t;
typedef unsigned int uint_t;

static __device__ __forceinline__ ushort_t f2b(float f) {
    uint_t u = __builtin_bit_cast(uint_t, f);
    uint_t r = (u + 0x7fffu + ((u >> 16) & 1u)) >> 16;   // RNE
    return (ushort_t)r;
}
static __device__ __forceinline__ float b2f(ushort_t u) {
    return __builtin_bit_cast(float, (uint_t)u << 16);
}

// ------------- weight transpose+convert: Wt[c*K+k] = bf16(W[k*N+c]) ----------
__global__ __launch_bounds__(256) void wt_k(const float* __restrict__ W,
                                            ushort_t* __restrict__ Wt,
                                            int K, int N) {
    int t = blockIdx.x * 256 + threadIdx.x;
    if (t < K * N) {
        int k = t / N, c = t % N;
        Wt[c * K + k] = f2b(W[t]);
    }
}

// ---------------- bf16 MFMA GEMM: C[M,N] = A[M,K] @ W[K,N] -------------------
// A: fp32 (AF32) or bf16, row-major. Wt: bf16 [N][K]. C: bf16 row-major.
template<int K, int N, bool AF32, bool RELU_BIAS>
__global__ __launch_bounds__(256) void gemm_mfma_k(const void* __restrict__ Ap,
                                                   const ushort_t* __restrict__ Wt,
                                                   const float* __restrict__ bias,
                                                   ushort_t* __restrict__ C, int M) {
    constexpr int BM = 128;
    constexpr int LDA = 40;                 // padded LDS stride (bf16 elems)
    constexpr int WN = (N == 128) ? 64 : 32;
    constexpr int MI = 4;                   // 4 x 16 = 64 rows / wave
    constexpr int NJ = WN / 16;             // 4 (N=128) or 2 (N=64)
    __shared__ ushort_t Alds[BM * LDA];

    const int tid  = threadIdx.x;
    const int lane = tid & 63;
    const int wid  = tid >> 6;
    const int wrow = wid >> 1;              // 0..1
    const int wcol = wid & 1;               // 0..1
    const int l15  = lane & 15;
    const int kg   = lane >> 4;             // 0..3
    const int row0 = blockIdx.x * BM;

    f32x4 acc[MI][NJ];
    #pragma unroll
    for (int i = 0; i < MI; ++i)
        #pragma unroll
        for (int j = 0; j < NJ; ++j)
            acc[i][j] = f32x4{0.f, 0.f, 0.f, 0.f};

    for (int k0 = 0; k0 < K; k0 += 32) {
        __syncthreads();
        // stage A tile: 128 rows x 32 cols bf16
        #pragma unroll
        for (int p = 0; p < 2; ++p) {
            int idx = tid + p * 256;
            int r = idx >> 2;
            int c8 = idx & 3;               // 8 bf16 elems each
            int gr = row0 + r;
            if (gr > M - 1) gr = M - 1;     // clamp (result rows discarded)
            if constexpr (AF32) {
                const float* A = (const float*)Ap;
                const float* pA = A + (size_t)gr * K + k0 + c8 * 8;
                float4 v0 = *reinterpret_cast<const float4*>(pA);
                float4 v1 = *reinterpret_cast<const float4*>(pA + 4);
                uint_t u0 = f2b(v0.x) | ((uint_t)f2b(v0.y) << 16);
                uint_t u1 = f2b(v0.z) | ((uint_t)f2b(v0.w) << 16);
                uint_t u2 = f2b(v1.x) | ((uint_t)f2b(v1.y) << 16);
                uint_t u3 = f2b(v1.z) | ((uint_t)f2b(v1.w) << 16);
                *reinterpret_cast<uint4*>(&Alds[r * LDA + c8 * 8]) = make_uint4(u0, u1, u2, u3);
            } else {
                const ushort_t* A = (const ushort_t*)Ap;
                uint4 v = *reinterpret_cast<const uint4*>(A + (size_t)gr * K + k0 + c8 * 8);
                *reinterpret_cast<uint4*>(&Alds[r * LDA + c8 * 8]) = v;
            }
        }
        __syncthreads();

        bf16x8 a[MI], b[NJ];
        #pragma unroll
        for (int i = 0; i < MI; ++i)
            a[i] = *reinterpret_cast<const bf16x8*>(&Alds[(wrow * 64 + i * 16 + l15) * LDA + kg * 8]);
        #pragma unroll
        for (int j = 0; j < NJ; ++j) {
            int col = wcol * WN + j * 16 + l15;
            b[j] = *reinterpret_cast<const bf16x8*>(Wt + (size_t)col * K + k0 + kg * 8);
        }
        #pragma unroll
        for (int i = 0; i < MI; ++i)
            #pragma unroll
            for (int j = 0; j < NJ; ++j)
                acc[i][j] = __builtin_amdgcn_mfma_f32_16x16x32_bf16(a[i], b[j], acc[i][j], 0, 0, 0);
    }

    // epilogue: C/D layout col=lane&15, row=(lane>>4)*4+reg
    #pragma unroll
    for (int i = 0; i < MI; ++i) {
        int rbase = row0 + wrow * 64 + i * 16 + kg * 4;
        #pragma unroll
        for (int j = 0; j < NJ; ++j) {
            int col = wcol * WN + j * 16 + l15;
            #pragma unroll
            for (int q = 0; q < 4; ++q) {
                int row = rbase + q;
                if (row < M) {
                    float val = acc[i][j][q];
                    if constexpr (RELU_BIAS) val = fmaxf(val + bias[col], 0.f);
                    C[(size_t)row * N + col] = f2b(val);
                }
            }
        }
    }
}

// ---------------- CSR build (unchanged from R1) ----------------
__global__ __launch_bounds__(256) void hist_k(const int* __restrict__ dst,
                                              int* __restrict__ deg) {
    int e = blockIdx.x * 256 + threadIdx.x;
    if (e < N_EDGES) atomicAdd(&deg[dst[e]], 1);
}

__global__ __launch_bounds__(256) void scan1_k(const int* __restrict__ deg,
                                               int* __restrict__ tmp,
                                               int* __restrict__ bsum) {
    __shared__ int s[256];
    int i = blockIdx.x * 256 + threadIdx.x;
    int t = threadIdx.x;
    s[t] = (i < N_NODES) ? deg[i] : 0;
    __syncthreads();
    for (int off = 1; off < 256; off <<= 1) {
        int v = (t >= off) ? s[t - off] : 0;
        __syncthreads();
        s[t] += v;
        __syncthreads();
    }
    if (i < N_NODES) tmp[i] = s[t];
    if (t == 255) bsum[blockIdx.x] = s[255];
}

__global__ __launch_bounds__(512) void scan2_k(int* __restrict__ bsum) {
    __shared__ int s[512];
    int t = threadIdx.x;
    s[t] = (t < NB_SCAN) ? bsum[t] : 0;
    __syncthreads();
    for (int off = 1; off < 512; off <<= 1) {
        int v = (t >= off) ? s[t - off] : 0;
        __syncthreads();
        s[t] += v;
        __syncthreads();
    }
    if (t < NB_SCAN) bsum[t] = s[t];
}

__global__ __launch_bounds__(256) void scan3_k(const int* __restrict__ tmp,
                                               const int* __restrict__ deg,
                                               const int* __restrict__ bsum,
                                               int* __restrict__ row_start) {
    int i = blockIdx.x * 256 + threadIdx.x;
    if (i >= N_NODES) return;
    int boff = (blockIdx.x > 0) ? bsum[blockIdx.x - 1] : 0;
    row_start[i] = tmp[i] - deg[i] + boff;
}

__global__ __launch_bounds__(256) void fill_k(const int* __restrict__ src,
                                              const int* __restrict__ dst,
                                              int* __restrict__ row_start,
                                              int* __restrict__ csr_src) {
    int e = blockIdx.x * 256 + threadIdx.x;
    if (e >= N_EDGES) return;
    int idx = atomicAdd(&row_start[dst[e]], 1);
    csr_src[idx] = src[e];
}

// ---------- gather + (1+eps)*own -> BN -> ReLU, D=128, bf16 I/O --------------
__global__ __launch_bounds__(256) void gather_bn_k(const ushort_t* __restrict__ Y,
                                                   const int* __restrict__ csr_src,
                                                   const int* __restrict__ row_end,
                                                   const int* __restrict__ deg,
                                                   const float* __restrict__ epsp,
                                                   const float* __restrict__ ba,
                                                   const float* __restrict__ g,
                                                   const float* __restrict__ be,
                                                   const float* __restrict__ m,
                                                   const float* __restrict__ v,
                                                   ushort_t* __restrict__ H) {
    int node = blockIdx.x * 4 + (threadIdx.x >> 6);
    int lane = threadIdx.x & 63;
    if (node >= N_NODES) return;
    int end = row_end[node];
    int d = deg[node];
    int c0 = lane * 2;
    float accx = 0.f, accy = 0.f;
    for (int j = end - d; j < end; ++j) {
        int s = csr_src[j];
        uint_t vv = *reinterpret_cast<const uint_t*>(Y + (size_t)s * 128 + c0);
        accx += b2f((ushort_t)(vv & 0xffff));
        accy += b2f((ushort_t)(vv >> 16));
    }
    float ep = 1.0f + epsp[0];
    uint_t ow = *reinterpret_cast<const uint_t*>(Y + (size_t)node * 128 + c0);
    float ox = b2f((ushort_t)(ow & 0xffff));
    float oy = b2f((ushort_t)(ow >> 16));
    float sc0 = g[c0] * rsqrtf(v[c0] + 1e-5f);
    float sc1 = g[c0 + 1] * rsqrtf(v[c0 + 1] + 1e-5f);
    float t0 = ep * ox + accx + ba[c0] - m[c0];
    float t1 = ep * oy + accy + ba[c0 + 1] - m[c0 + 1];
    float r0 = fmaxf(t0 * sc0 + be[c0], 0.f);
    float r1 = fmaxf(t1 * sc1 + be[c0 + 1], 0.f);
    uint_t packed = (uint_t)f2b(r0) | ((uint_t)f2b(r1) << 16);
    *reinterpret_cast<uint_t*>(H + (size_t)node * 128 + c0) = packed;
}

// ---------------- pool (batch sorted): per-thread running sums ---------------
__global__ __launch_bounds__(256) void pool_k(const ushort_t* __restrict__ h,
                                              const int* __restrict__ batch,
                                              float* __restrict__ pooled) {
    int c = threadIdx.x & 63;
    int r = threadIdx.x >> 6;
    int n0 = blockIdx.x * 256 + r * 64;
    float acc = 0.f;
    int cur = -1;
    for (int i = 0; i < 64; ++i) {
        int n = n0 + i;
        if (n >= N_NODES) break;
        int b = batch[n];
        if (b != cur) {
            if (cur >= 0) atomicAdd(&pooled[cur * 64 + c], acc);
            acc = 0.f;
            cur = b;
        }
        acc += b2f(h[(size_t)n * 64 + c]);
    }
    if (cur >= 0) atomicAdd(&pooled[cur * 64 + c], acc);
}

// ---------------- classifier ----------------
__global__ __launch_bounds__(256) void classifier_k(const float* __restrict__ pooled,
                                                    const float* __restrict__ wc,
                                                    const float* __restrict__ bc,
                                                    float* __restrict__ out) {
    int t = threadIdx.x;
    int gidx = t >> 1, c = t & 1;
    float s = bc[c];
    #pragma unroll
    for (int k = 0; k < 64; ++k)
        s += pooled[gidx * 64 + k] * wc[k * 2 + c];
    out[gidx * 2 + c] = s;
}

extern "C" void kernel_launch(void* const* d_in, const int* in_sizes, int n_in,
                              void* d_out, int out_size, void* d_ws, size_t ws_size,
                              hipStream_t stream) {
    const float* x     = (const float*)d_in[0];
    const int*   ei    = (const int*)d_in[1];
    const int*   src   = ei;
    const int*   dst   = ei + N_EDGES;
    const int*   batch = (const int*)d_in[2];
    const float* eps1 = (const float*)d_in[3];
    const float* w1a  = (const float*)d_in[4];
    const float* b1a  = (const float*)d_in[5];
    const float* g1   = (const float*)d_in[6];
    const float* be1  = (const float*)d_in[7];
    const float* m1   = (const float*)d_in[8];
    const float* v1   = (const float*)d_in[9];
    const float* w1b  = (const float*)d_in[10];
    const float* b1b  = (const float*)d_in[11];
    const float* eps2 = (const float*)d_in[12];
    const float* w2a  = (const float*)d_in[13];
    const float* b2a  = (const float*)d_in[14];
    const float* g2   = (const float*)d_in[15];
    const float* be2  = (const float*)d_in[16];
    const float* m2   = (const float*)d_in[17];
    const float* v2   = (const float*)d_in[18];
    const float* w2b  = (const float*)d_in[19];
    const float* b2b  = (const float*)d_in[20];
    const float* eps3 = (const float*)d_in[21];
    const float* w3a  = (const float*)d_in[22];
    const float* b3a  = (const float*)d_in[23];
    const float* g3   = (const float*)d_in[24];
    const float* be3  = (const float*)d_in[25];
    const float* m3   = (const float*)d_in[26];
    const float* v3   = (const float*)d_in[27];
    const float* w3b  = (const float*)d_in[28];
    const float* b3b  = (const float*)d_in[29];
    const float* wc   = (const float*)d_in[30];
    const float* bc   = (const float*)d_in[31];
    float* out = (float*)d_out;

    // workspace layout
    ushort_t* Y = (ushort_t*)d_ws;             // [100000,128] bf16 (also final [100000,64])
    ushort_t* H = Y + 12800000;                // [100000,128] bf16
    ushort_t* wt1a = H + 12800000;             // 384*128
    ushort_t* wt1b = wt1a + 49152;             // 128*128
    ushort_t* wt2a = wt1b + 16384;
    ushort_t* wt2b = wt2a + 16384;
    ushort_t* wt3a = wt2b + 16384;
    ushort_t* wt3b = wt3a + 16384;             // 128*64
    float* pooled = (float*)(wt3b + 8192);     // [128,64]
    int* ideg = (int*)(pooled + 8192);         // [100000]
    int* irow = ideg + N_NODES;
    int* itmp = irow + N_NODES;
    int* icsr = itmp + N_NODES;                // [800000]
    int* ibsum = icsr + N_EDGES;               // [391]

    const int M = N_NODES;
    const int gGemm = (M + 127) / 128;         // 782
    const int gEdge = (N_EDGES + 255) / 256;   // 3125
    const int gNode = NB_SCAN;                 // 391
    const int gGath = (M + 3) / 4;             // 25000

    // ---- weight transpose+convert (tiny) ----
    wt_k<<<192, 256, 0, stream>>>(w1a, wt1a, 384, 128);
    wt_k<<<64, 256, 0, stream>>>(w1b, wt1b, 128, 128);
    wt_k<<<64, 256, 0, stream>>>(w2a, wt2a, 128, 128);
    wt_k<<<64, 256, 0, stream>>>(w2b, wt2b, 128, 128);
    wt_k<<<64, 256, 0, stream>>>(w3a, wt3a, 128, 128);
    wt_k<<<32, 256, 0, stream>>>(w3b, wt3b, 128, 64);

    // ---- build CSR (once, reused by all 3 layers) ----
    hipMemsetAsync(ideg, 0, N_NODES * sizeof(int), stream);
    hist_k<<<gEdge, 256, 0, stream>>>(dst, ideg);
    scan1_k<<<gNode, 256, 0, stream>>>(ideg, itmp, ibsum);
    scan2_k<<<1, 512, 0, stream>>>(ibsum);
    scan3_k<<<gNode, 256, 0, stream>>>(itmp, ideg, ibsum, irow);
    fill_k<<<gEdge, 256, 0, stream>>>(src, dst, irow, icsr);

    // ---- layer 1 ----
    gemm_mfma_k<384, 128, true,  false><<<gGemm, 256, 0, stream>>>(x, wt1a, nullptr, Y, M);
    gather_bn_k<<<gGath, 256, 0, stream>>>(Y, icsr, irow, ideg, eps1, b1a, g1, be1, m1, v1, H);
    gemm_mfma_k<128, 128, false, true><<<gGemm, 256, 0, stream>>>(H, wt1b, b1b, H, M);

    // ---- layer 2 ----
    gemm_mfma_k<128, 128, false, false><<<gGemm, 256, 0, stream>>>(H, wt2a, nullptr, Y, M);
    gather_bn_k<<<gGath, 256, 0, stream>>>(Y, icsr, irow, ideg, eps2, b2a, g2, be2, m2, v2, H);
    gemm_mfma_k<128, 128, false, true><<<gGemm, 256, 0, stream>>>(H, wt2b, b2b, H, M);

    // ---- layer 3 ----
    gemm_mfma_k<128, 128, false, false><<<gGemm, 256, 0, stream>>>(H, wt3a, nullptr, Y, M);
    gather_bn_k<<<gGath, 256, 0, stream>>>(Y, icsr, irow, ideg, eps3, b3a, g3, be3, m3, v3, H);
    gemm_mfma_k<128, 64, false, true><<<gGemm, 256, 0, stream>>>(H, wt3b, b3b, Y, M);  // [M,64] -> Y

    // ---- pool + classifier ----
    hipMemsetAsync(pooled, 0, (size_t)N_GRAPHS * 64 * sizeof(float), stream);
    pool_k<<<gNode, 256, 0, stream>>>(Y, batch, pooled);
    classifier_k<<<1, 256, 0, stream>>>(pooled, wc, bc, out);
}